// Round 1
// baseline (938.389 us; speedup 1.0000x reference)
//
#include <hip/hip_runtime.h>
#include <hip/hip_bf16.h>
#include <stdint.h>

#define NN 100000
#define NE 1600000
#define DD 128

// ---------------- Phase 1a: histogram of rows ----------------
__global__ void k_count(const int* __restrict__ row, int* __restrict__ counts) {
  int stride = gridDim.x * blockDim.x;
  for (int i = blockIdx.x * blockDim.x + threadIdx.x; i < NE; i += stride)
    atomicAdd(&counts[row[i]], 1);
}

// ---------------- Phase 1b: exclusive scan (single block) ----------------
__global__ __launch_bounds__(1024) void k_scan(const int* __restrict__ counts,
                                               int* __restrict__ offsets,
                                               int* __restrict__ cursor) {
  __shared__ int wsum[16];
  const int t = threadIdx.x;
  const int lane = t & 63, wid = t >> 6;
  int running = 0;
  const int ntiles = (NN + 1023) >> 10;
  for (int tile = 0; tile < ntiles; ++tile) {
    int i = (tile << 10) + t;
    int v = (i < NN) ? counts[i] : 0;
    int incl = v;
#pragma unroll
    for (int d = 1; d < 64; d <<= 1) {
      int u = __shfl_up(incl, d, 64);
      if (lane >= d) incl += u;
    }
    if (lane == 63) wsum[wid] = incl;
    __syncthreads();
    if (wid == 0) {
      int w = (lane < 16) ? wsum[lane] : 0;
#pragma unroll
      for (int d = 1; d < 16; d <<= 1) {
        int u = __shfl_up(w, d, 64);
        if (lane >= d) w += u;
      }
      if (lane < 16) wsum[lane] = w;  // inclusive scan of per-wave sums
    }
    __syncthreads();
    int wbase = wid ? wsum[wid - 1] : 0;
    if (i < NN) {
      int excl = running + wbase + (incl - v);
      offsets[i] = excl;
      cursor[i] = excl;
    }
    running += wsum[15];
    __syncthreads();  // protect wsum before next tile overwrites
  }
  if (t == 0) offsets[NN] = running;
}

// ---------------- Phase 1c: scatter edge ids into CSR order ----------------
__global__ void k_scatter(const int* __restrict__ row, int* __restrict__ cursor,
                          int* __restrict__ csr_e) {
  int stride = gridDim.x * blockDim.x;
  for (int i = blockIdx.x * blockDim.x + threadIdx.x; i < NE; i += stride) {
    int pos = atomicAdd(&cursor[row[i]], 1);
    csr_e[pos] = i;
  }
}

// ---------------- Phase 1d: segmented SpMM, one wave per node ----------------
__global__ __launch_bounds__(256) void k_spmm(
    const int* __restrict__ offsets, const int* __restrict__ csr_e,
    const int* __restrict__ col, const float* __restrict__ val,
    const float* __restrict__ emb, float* __restrict__ rel) {
  const int lane = threadIdx.x & 63;
  const int node = blockIdx.x * 4 + (threadIdx.x >> 6);
  if (node >= NN) return;
  const int beg = offsets[node], end = offsets[node + 1];
  float ax = 0.f, ay = 0.f;
  for (int j = beg; j < end; ++j) {
    int e = csr_e[j];               // wave-uniform load (HW broadcast)
    int c = col[e];
    float v = val[e];
    const float2 ev = *(const float2*)(emb + (size_t)c * DD + lane * 2);
    ax = fmaf(v, ev.x, ax);
    ay = fmaf(v, ev.y, ay);
  }
  *(float2*)(rel + (size_t)node * DD + lane * 2) = make_float2(ax, ay);
}

// ---------------- Phase 2: out = rel@W1 + (rel*emb)@W2 ----------------
// W1,W2 staged as bf16 in LDS (64 KiB total). Thread computes 4 rows x 2 cols.
__global__ __launch_bounds__(512) void k_phase2(
    const float* __restrict__ rel, const float* __restrict__ emb,
    const float* __restrict__ W1, const float* __restrict__ W2,
    float* __restrict__ out) {
  __shared__ __hip_bfloat162 w1s[DD * DD / 2];
  __shared__ __hip_bfloat162 w2s[DD * DD / 2];
  for (int i = threadIdx.x; i < DD * DD / 2; i += 512) {
    __hip_bfloat162 a, b;
    a.x = __float2bfloat16(W1[2 * i]);
    a.y = __float2bfloat16(W1[2 * i + 1]);
    b.x = __float2bfloat16(W2[2 * i]);
    b.y = __float2bfloat16(W2[2 * i + 1]);
    w1s[i] = a;
    w2s[i] = b;
  }
  __syncthreads();

  const int lane = threadIdx.x & 63;
  const int wid = threadIdx.x >> 6;
  const int c0 = lane * 2;
  const int r0 = blockIdx.x * 32 + wid;  // rows r0, r0+8, r0+16, r0+24

  float acc0[4] = {0.f, 0.f, 0.f, 0.f};
  float acc1[4] = {0.f, 0.f, 0.f, 0.f};

  for (int k = 0; k < DD; k += 2) {
    float2 w1a = __bfloat1622float2(w1s[k * 64 + lane]);        // W1[k][c0,c0+1]
    float2 w1b = __bfloat1622float2(w1s[(k + 1) * 64 + lane]);  // W1[k+1][..]
    float2 w2a = __bfloat1622float2(w2s[k * 64 + lane]);
    float2 w2b = __bfloat1622float2(w2s[(k + 1) * 64 + lane]);
#pragma unroll
    for (int i = 0; i < 4; ++i) {
      const size_t base = (size_t)(r0 + i * 8) * DD + k;
      float2 rv = *(const float2*)(rel + base);  // wave-uniform broadcast
      float2 ev = *(const float2*)(emb + base);
      float rex = rv.x * ev.x;
      float rey = rv.y * ev.y;
      acc0[i] += rv.x * w1a.x + rex * w2a.x + rv.y * w1b.x + rey * w2b.x;
      acc1[i] += rv.x * w1a.y + rex * w2a.y + rv.y * w1b.y + rey * w2b.y;
    }
  }
#pragma unroll
  for (int i = 0; i < 4; ++i) {
    *(float2*)(out + (size_t)(r0 + i * 8) * DD + c0) =
        make_float2(acc0[i], acc1[i]);
  }
}

extern "C" void kernel_launch(void* const* d_in, const int* in_sizes, int n_in,
                              void* d_out, int out_size, void* d_ws, size_t ws_size,
                              hipStream_t stream) {
  const float* emb  = (const float*)d_in[0];
  const int*   erow = (const int*)d_in[1];
  const int*   ecol = (const int*)d_in[2];
  const float* eva  = (const float*)d_in[3];
  const float* W1   = (const float*)d_in[4];
  const float* W2   = (const float*)d_in[5];
  float* out = (float*)d_out;

  // workspace layout (bytes):
  //   rel     @ 0          : 100000*128*4 = 51,200,000
  //   counts  @ 51,200,000 : 400,000
  //   offsets @ 51,600,000 : 400,004 (+pad)
  //   cursor  @ 52,000,128 : 400,000
  //   csr_e   @ 52,400,128 : 6,400,000   -> total 58,800,128
  char* ws = (char*)d_ws;
  float* rel    = (float*)(ws);
  int* counts   = (int*)(ws + 51200000);
  int* offsets  = (int*)(ws + 51600000);
  int* cursor   = (int*)(ws + 52000128);
  int* csr_e    = (int*)(ws + 52400128);

  hipMemsetAsync(counts, 0, NN * sizeof(int), stream);
  k_count<<<1024, 256, 0, stream>>>(erow, counts);
  k_scan<<<1, 1024, 0, stream>>>(counts, offsets, cursor);
  k_scatter<<<1024, 256, 0, stream>>>(erow, cursor, csr_e);
  k_spmm<<<(NN + 3) / 4, 256, 0, stream>>>(offsets, csr_e, ecol, eva, emb, rel);
  k_phase2<<<NN / 32, 512, 0, stream>>>(rel, emb, W1, W2, out);
}

// Round 2
// 408.608 us; speedup vs baseline: 2.2965x; 2.2965x over previous
//
#include <hip/hip_runtime.h>
#include <hip/hip_bf16.h>
#include <stdint.h>

#define NN 100000
#define NE 1600000
#define DD 128
#define NBLK 98  // ceil(NN/1024)

typedef __attribute__((ext_vector_type(8))) short short8;  // 8 bf16 (4 VGPRs)
typedef __attribute__((ext_vector_type(4))) float f32x4;   // MFMA C/D frag

__device__ inline unsigned bf16bits(float x) {
  __hip_bfloat16 h = __float2bfloat16(x);
  return (unsigned)*reinterpret_cast<unsigned short*>(&h);
}

// ---------------- Phase 1a: histogram of rows ----------------
__global__ void k_count(const int* __restrict__ row, int* __restrict__ counts) {
  int stride = gridDim.x * blockDim.x;
  for (int i = blockIdx.x * blockDim.x + threadIdx.x; i < NE; i += stride)
    atomicAdd(&counts[row[i]], 1);
}

// ---------------- Phase 1b: hierarchical exclusive scan ----------------
__global__ __launch_bounds__(1024) void k_scan1(const int* __restrict__ counts,
                                                int* __restrict__ offsets,
                                                int* __restrict__ bsum) {
  __shared__ int wsum[16];
  const int t = threadIdx.x, lane = t & 63, wid = t >> 6;
  int i = blockIdx.x * 1024 + t;
  int v = (i < NN) ? counts[i] : 0;
  int incl = v;
#pragma unroll
  for (int d = 1; d < 64; d <<= 1) {
    int u = __shfl_up(incl, d, 64);
    if (lane >= d) incl += u;
  }
  if (lane == 63) wsum[wid] = incl;
  __syncthreads();
  if (wid == 0) {
    int w = (lane < 16) ? wsum[lane] : 0;
#pragma unroll
    for (int d = 1; d < 16; d <<= 1) {
      int u = __shfl_up(w, d, 64);
      if (lane >= d) w += u;
    }
    if (lane < 16) wsum[lane] = w;
  }
  __syncthreads();
  int wbase = wid ? wsum[wid - 1] : 0;
  if (i < NN) offsets[i] = wbase + incl - v;
  if (t == 0) bsum[blockIdx.x] = wsum[15];
}

__global__ void k_scan2(const int* __restrict__ bsum, int* __restrict__ bpre) {
  const int lane = threadIdx.x;  // 64 threads
  int a = bsum[lane];            // lanes 0..63 all valid (NBLK=98)
  int b = (lane + 64 < NBLK) ? bsum[lane + 64] : 0;
  int sa = a, sb = b;
#pragma unroll
  for (int d = 1; d < 64; d <<= 1) {
    int u = __shfl_up(sa, d, 64);
    if (lane >= d) sa += u;
    u = __shfl_up(sb, d, 64);
    if (lane >= d) sb += u;
  }
  int totA = __shfl(sa, 63, 64);
  bpre[lane] = sa - a;
  if (lane + 64 < NBLK) bpre[lane + 64] = totA + sb - b;
}

__global__ __launch_bounds__(1024) void k_scan3(int* __restrict__ offsets,
                                                int* __restrict__ cursor,
                                                const int* __restrict__ bpre) {
  int i = blockIdx.x * 1024 + threadIdx.x;
  if (i < NN) {
    int o = offsets[i] + bpre[blockIdx.x];
    offsets[i] = o;
    cursor[i] = o;
  }
  if (i == 0) offsets[NN] = NE;
}

// ---------------- Phase 1c: scatter edge ids into CSR order ----------------
__global__ void k_scatter(const int* __restrict__ row, int* __restrict__ cursor,
                          int* __restrict__ csr_e) {
  int stride = gridDim.x * blockDim.x;
  for (int i = blockIdx.x * blockDim.x + threadIdx.x; i < NE; i += stride) {
    int pos = atomicAdd(&cursor[row[i]], 1);
    csr_e[pos] = i;
  }
}

// ---------------- Phase 1d: SpMM, one wave per node, emit bf16 [rel|re] ----
__global__ __launch_bounds__(256) void k_spmm(
    const int* __restrict__ offsets, const int* __restrict__ csr_e,
    const int* __restrict__ col, const float* __restrict__ val,
    const float* __restrict__ emb, int* __restrict__ A /* [NN][128] ints */) {
  const int lane = threadIdx.x & 63;
  const int node = blockIdx.x * 4 + (threadIdx.x >> 6);
  if (node >= NN) return;
  const int beg = offsets[node], end = offsets[node + 1];
  float ax = 0.f, ay = 0.f;
  for (int j0 = beg; j0 < end; j0 += 64) {
    int idx = j0 + lane;
    int c = 0;
    float v = 0.f;
    if (idx < end) {
      int e = csr_e[idx];   // coalesced
      c = col[e];           // batched gather (2 per 64 edges)
      v = val[e];
    }
    int n = min(end - j0, 64);
    for (int t = 0; t < n; ++t) {
      int ct = __shfl(c, t, 64);
      float vt = __shfl(v, t, 64);
      const float2 ev = *(const float2*)(emb + (size_t)ct * DD + (lane << 1));
      ax = fmaf(vt, ev.x, ax);
      ay = fmaf(vt, ev.y, ay);
    }
  }
  // epilogue: A row = [rel(128) | rel*emb(128)] as bf16
  const float2 e = *(const float2*)(emb + (size_t)node * DD + (lane << 1));
  float rx = ax * e.x, ry = ay * e.y;
  int* Arow = A + (size_t)node * 128;
  Arow[lane] = bf16bits(ax) | (bf16bits(ay) << 16);
  Arow[64 + lane] = bf16bits(rx) | (bf16bits(ry) << 16);
}

// ---------------- W pack: B-fragment layout for MFMA ----------------
// chunk cid in [0,4096): lane=cid&63, ct=(cid>>6)&7, ks=cid>>9
// lane holds Wbig[ks*32 + (lane>>4)*8 + j][ct*16 + (lane&15)], j=0..7
__global__ void k_packw(const float* __restrict__ W1, const float* __restrict__ W2,
                        uint4* __restrict__ wpack) {
  int cid = blockIdx.x * 256 + threadIdx.x;
  if (cid >= 4096) return;
  int lane = cid & 63, ct = (cid >> 6) & 7, ks = cid >> 9;
  int colc = ct * 16 + (lane & 15);
  int k0 = ks * 32 + (lane >> 4) * 8;
  unsigned h[8];
#pragma unroll
  for (int j = 0; j < 8; ++j) {
    int kk = k0 + j;
    float w = (kk < DD) ? W1[kk * DD + colc] : W2[(kk - DD) * DD + colc];
    h[j] = bf16bits(w);
  }
  uint4 u;
  u.x = h[0] | (h[1] << 16);
  u.y = h[2] | (h[3] << 16);
  u.z = h[4] | (h[5] << 16);
  u.w = h[6] | (h[7] << 16);
  wpack[cid] = u;
}

// ---------------- Phase 2: out[M,128] = A[M,256]bf16 @ Wbig[256,128]bf16 ----
__global__ __launch_bounds__(256) void k_phase2(
    const short* __restrict__ A, const uint4* __restrict__ wpack,
    float* __restrict__ out) {
  __shared__ uint4 bw[4096];  // 64 KiB: B frags [ks][ct][lane]
  for (int i = threadIdx.x; i < 4096; i += 256) bw[i] = wpack[i];
  __syncthreads();

  const int lane = threadIdx.x & 63;
  const int wid = threadIdx.x >> 6;
  const long Rw = (long)blockIdx.x * 128 + wid * 32;  // wave's 32 rows

  long r0 = Rw + (lane & 15);
  long r1 = r0 + 16;
  if (r0 >= NN) r0 = NN - 1;  // clamp; stores are guarded
  if (r1 >= NN) r1 = NN - 1;
  const short* a0p = A + r0 * 256 + (lane >> 4) * 8;
  const short* a1p = A + r1 * 256 + (lane >> 4) * 8;

  f32x4 acc[2][8] = {};

#pragma unroll
  for (int ks = 0; ks < 8; ++ks) {
    short8 a0 = *(const short8*)(a0p + ks * 32);
    short8 a1 = *(const short8*)(a1p + ks * 32);
#pragma unroll
    for (int ct = 0; ct < 8; ++ct) {
      short8 b = *(const short8*)&bw[(ks * 8 + ct) * 64 + lane];
      acc[0][ct] = __builtin_amdgcn_mfma_f32_16x16x32_bf16(a0, b, acc[0][ct], 0, 0, 0);
      acc[1][ct] = __builtin_amdgcn_mfma_f32_16x16x32_bf16(a1, b, acc[1][ct], 0, 0, 0);
    }
  }

  // C/D layout: col = lane&15, row = (lane>>4)*4 + reg  [m89-verified]
  const int orow = (lane >> 4) * 4;
  const int ocol = lane & 15;
#pragma unroll
  for (int rt = 0; rt < 2; ++rt) {
    long rbase = Rw + rt * 16 + orow;
#pragma unroll
    for (int ct = 0; ct < 8; ++ct) {
#pragma unroll
      for (int q = 0; q < 4; ++q) {
        long rr = rbase + q;
        if (rr < NN) out[rr * DD + ct * 16 + ocol] = acc[rt][ct][q];
      }
    }
  }
}

extern "C" void kernel_launch(void* const* d_in, const int* in_sizes, int n_in,
                              void* d_out, int out_size, void* d_ws, size_t ws_size,
                              hipStream_t stream) {
  const float* emb = (const float*)d_in[0];
  const int* erow = (const int*)d_in[1];
  const int* ecol = (const int*)d_in[2];
  const float* eva = (const float*)d_in[3];
  const float* W1 = (const float*)d_in[4];
  const float* W2 = (const float*)d_in[5];
  float* out = (float*)d_out;

  // workspace layout (bytes), total 58,466,688:
  //   A       @ 0          : 100000*256*2 = 51,200,000  (bf16 [rel|re])
  //   offsets @ 51,200,000 : 400,128 (100001 ints + pad)
  //   counts  @ 51,600,128 : 400,000  (aliased: cursor after scan1)
  //   csr_e   @ 52,000,128 : 6,400,000
  //   bsum    @ 58,400,128 : 512
  //   bpre    @ 58,400,640 : 512
  //   wpack   @ 58,401,152 : 65,536
  char* ws = (char*)d_ws;
  short* A = (short*)(ws);
  int* offsets = (int*)(ws + 51200000);
  int* counts = (int*)(ws + 51600128);
  int* cursor = counts;  // counts dead after k_scan1
  int* csr_e = (int*)(ws + 52000128);
  int* bsum = (int*)(ws + 58400128);
  int* bpre = (int*)(ws + 58400640);
  uint4* wpack = (uint4*)(ws + 58401152);

  hipMemsetAsync(counts, 0, NN * sizeof(int), stream);
  k_count<<<1024, 256, 0, stream>>>(erow, counts);
  k_scan1<<<NBLK, 1024, 0, stream>>>(counts, offsets, bsum);
  k_scan2<<<1, 64, 0, stream>>>(bsum, bpre);
  k_scan3<<<NBLK, 1024, 0, stream>>>(offsets, cursor, bpre);
  k_scatter<<<1024, 256, 0, stream>>>(erow, cursor, csr_e);
  k_packw<<<16, 256, 0, stream>>>(W1, W2, wpack);
  k_spmm<<<NN / 4, 256, 0, stream>>>(offsets, csr_e, ecol, eva, emb, (int*)A);
  k_phase2<<<(NN + 127) / 128, 256, 0, stream>>>(A, wpack, out);
}

// Round 3
// 296.077 us; speedup vs baseline: 3.1694x; 1.3801x over previous
//
#include <hip/hip_runtime.h>
#include <hip/hip_bf16.h>
#include <stdint.h>

#define NN 100000
#define NE 1600000
#define DD 128
#define NBLK 98  // ceil(NN/1024)

typedef __attribute__((ext_vector_type(8))) short short8;  // 8 bf16 (4 VGPRs)
typedef __attribute__((ext_vector_type(4))) float f32x4;   // MFMA C/D frag

__device__ inline unsigned bf16bits(float x) {
  __hip_bfloat16 h = __float2bfloat16(x);
  return (unsigned)*reinterpret_cast<unsigned short*>(&h);
}

__device__ inline float bfhi(unsigned u) { return __uint_as_float(u & 0xffff0000u); }
__device__ inline float bflo(unsigned u) { return __uint_as_float(u << 16); }

// ---------------- emb -> bf16 table ----------------
__global__ __launch_bounds__(256) void k_cvt(const float* __restrict__ emb,
                                             uint4* __restrict__ tbl) {
  int i = blockIdx.x * 256 + threadIdx.x;  // 1.6M threads, 8 elems each
  const float4 a = ((const float4*)emb)[2 * i];
  const float4 b = ((const float4*)emb)[2 * i + 1];
  uint4 u;
  u.x = bf16bits(a.x) | (bf16bits(a.y) << 16);
  u.y = bf16bits(a.z) | (bf16bits(a.w) << 16);
  u.z = bf16bits(b.x) | (bf16bits(b.y) << 16);
  u.w = bf16bits(b.z) | (bf16bits(b.w) << 16);
  tbl[i] = u;
}

// ---------------- Phase 1a: histogram of rows ----------------
__global__ void k_count(const int* __restrict__ row, int* __restrict__ counts) {
  int stride = gridDim.x * blockDim.x;
  for (int i = blockIdx.x * blockDim.x + threadIdx.x; i < NE; i += stride)
    atomicAdd(&counts[row[i]], 1);
}

// ---------------- Phase 1b: hierarchical exclusive scan ----------------
__global__ __launch_bounds__(1024) void k_scan1(const int* __restrict__ counts,
                                                int* __restrict__ offsets,
                                                int* __restrict__ bsum) {
  __shared__ int wsum[16];
  const int t = threadIdx.x, lane = t & 63, wid = t >> 6;
  int i = blockIdx.x * 1024 + t;
  int v = (i < NN) ? counts[i] : 0;
  int incl = v;
#pragma unroll
  for (int d = 1; d < 64; d <<= 1) {
    int u = __shfl_up(incl, d, 64);
    if (lane >= d) incl += u;
  }
  if (lane == 63) wsum[wid] = incl;
  __syncthreads();
  if (wid == 0) {
    int w = (lane < 16) ? wsum[lane] : 0;
#pragma unroll
    for (int d = 1; d < 16; d <<= 1) {
      int u = __shfl_up(w, d, 64);
      if (lane >= d) w += u;
    }
    if (lane < 16) wsum[lane] = w;
  }
  __syncthreads();
  int wbase = wid ? wsum[wid - 1] : 0;
  if (i < NN) offsets[i] = wbase + incl - v;
  if (t == 0) bsum[blockIdx.x] = wsum[15];
}

__global__ void k_scan2(const int* __restrict__ bsum, int* __restrict__ bpre) {
  const int lane = threadIdx.x;  // 64 threads
  int a = bsum[lane];
  int b = (lane + 64 < NBLK) ? bsum[lane + 64] : 0;
  int sa = a, sb = b;
#pragma unroll
  for (int d = 1; d < 64; d <<= 1) {
    int u = __shfl_up(sa, d, 64);
    if (lane >= d) sa += u;
    u = __shfl_up(sb, d, 64);
    if (lane >= d) sb += u;
  }
  int totA = __shfl(sa, 63, 64);
  bpre[lane] = sa - a;
  if (lane + 64 < NBLK) bpre[lane + 64] = totA + sb - b;
}

__global__ __launch_bounds__(1024) void k_scan3(int* __restrict__ offsets,
                                                int* __restrict__ cursor,
                                                const int* __restrict__ bpre) {
  int i = blockIdx.x * 1024 + threadIdx.x;
  if (i < NN) {
    int o = offsets[i] + bpre[blockIdx.x];
    offsets[i] = o;
    cursor[i] = o;
  }
  if (i == 0) offsets[NN] = NE;
}

// ---------------- Phase 1c: scatter packed (col,val) into CSR order --------
// pack: (col << 15) | round(val * 32767); col < 2^17, val in [0,1)
__global__ void k_scatter(const int* __restrict__ row, const int* __restrict__ col,
                          const float* __restrict__ val, int* __restrict__ cursor,
                          unsigned* __restrict__ cpack) {
  int stride = gridDim.x * blockDim.x;
  for (int i = blockIdx.x * blockDim.x + threadIdx.x; i < NE; i += stride) {
    int pos = atomicAdd(&cursor[row[i]], 1);
    unsigned q = (unsigned)__float2int_rn(val[i] * 32767.0f);
    cpack[pos] = ((unsigned)col[i] << 15) | q;
  }
}

// ---------------- Phase 1d: SpMM, one wave per node, bf16 gathers ----------
__global__ __launch_bounds__(256) void k_spmm(
    const int* __restrict__ offsets, const unsigned* __restrict__ cpack,
    const unsigned short* __restrict__ tbl, unsigned* __restrict__ rel) {
  const int lane = threadIdx.x & 63;
  const int node = blockIdx.x * 4 + (threadIdx.x >> 6);
  if (node >= NN) return;
  const int beg = offsets[node], end = offsets[node + 1];
  float ax = 0.f, ay = 0.f;
  for (int j0 = beg; j0 < end; j0 += 64) {
    int idx = j0 + lane;
    unsigned pk = (idx < end) ? cpack[idx] : 0u;  // coalesced; 0 => c=0,v=0
    int n4 = (min(end - j0, 64) + 3) & ~3;
    for (int t = 0; t < n4; t += 4) {
#pragma unroll
      for (int s = 0; s < 4; ++s) {  // 4 independent gathers in flight
        unsigned u = (unsigned)__shfl((int)pk, t + s, 64);
        unsigned c = u >> 15;
        float v = (float)(u & 32767u) * (1.0f / 32767.0f);
        unsigned w = *(const unsigned*)(tbl + ((size_t)c << 7) + (lane << 1));
        ax = fmaf(v, bflo(w), ax);
        ay = fmaf(v, bfhi(w), ay);
      }
    }
  }
  rel[(size_t)node * 64 + lane] = bf16bits(ax) | (bf16bits(ay) << 16);
}

// ---------------- W pack: B-fragment layout for MFMA ----------------
// cid in [0,4096): lane=cid&63, ct=(cid>>6)&7, ks=cid>>9
// lane holds Wbig[ks*32 + (lane>>4)*8 + j][ct*16 + (lane&15)], j=0..7
// Wbig = [W1; W2] (256 x 128)
__global__ void k_packw(const float* __restrict__ W1, const float* __restrict__ W2,
                        uint4* __restrict__ wpack) {
  int cid = blockIdx.x * 256 + threadIdx.x;
  if (cid >= 4096) return;
  int lane = cid & 63, ct = (cid >> 6) & 7, ks = cid >> 9;
  int colc = ct * 16 + (lane & 15);
  int k0 = ks * 32 + (lane >> 4) * 8;
  unsigned h[8];
#pragma unroll
  for (int j = 0; j < 8; ++j) {
    int kk = k0 + j;
    float w = (kk < DD) ? W1[kk * DD + colc] : W2[(kk - DD) * DD + colc];
    h[j] = bf16bits(w);
  }
  uint4 u;
  u.x = h[0] | (h[1] << 16);
  u.y = h[2] | (h[3] << 16);
  u.z = h[4] | (h[5] << 16);
  u.w = h[6] | (h[7] << 16);
  wpack[cid] = u;
}

// elementwise bf16 product of two 8-wide bf16 frags (f32 mul, RNE repack)
__device__ inline short8 bfmul8(short8 a, short8 b) {
  short8 r;
#pragma unroll
  for (int i = 0; i < 8; ++i) {
    float fa = __uint_as_float(((unsigned)(unsigned short)a[i]) << 16);
    float fb = __uint_as_float(((unsigned)(unsigned short)b[i]) << 16);
    r[i] = (short)bf16bits(fa * fb);
  }
  return r;
}

// ---------------- Phase 2: out = rel@W1 + (rel.*emb)@W2, MFMA -------------
__global__ __launch_bounds__(256) void k_phase2(
    const unsigned short* __restrict__ rel, const unsigned short* __restrict__ tbl,
    const uint4* __restrict__ wpack, float* __restrict__ out) {
  __shared__ uint4 bw[4096];  // 64 KiB: B frags [ks(8)][ct(8)][lane(64)]
  for (int i = threadIdx.x; i < 4096; i += 256) bw[i] = wpack[i];
  __syncthreads();

  const int lane = threadIdx.x & 63;
  const int wid = threadIdx.x >> 6;
  const long Rw = (long)blockIdx.x * 128 + wid * 32;  // wave's 32 rows

  long r0 = Rw + (lane & 15);
  long r1 = r0 + 16;
  if (r0 >= NN) r0 = NN - 1;  // clamp; stores are guarded
  if (r1 >= NN) r1 = NN - 1;
  const int fo = (lane >> 4) * 8;  // frag k-offset within 32-subtile

  f32x4 acc[2][8] = {};

#pragma unroll
  for (int ks = 0; ks < 4; ++ks) {
    short8 rf0 = *(const short8*)(rel + r0 * DD + ks * 32 + fo);
    short8 ef0 = *(const short8*)(tbl + r0 * DD + ks * 32 + fo);
    short8 rf1 = *(const short8*)(rel + r1 * DD + ks * 32 + fo);
    short8 ef1 = *(const short8*)(tbl + r1 * DD + ks * 32 + fo);
    short8 m0 = bfmul8(rf0, ef0);
    short8 m1 = bfmul8(rf1, ef1);
#pragma unroll
    for (int ct = 0; ct < 8; ++ct) {
      short8 b1 = *(const short8*)&bw[(ks * 8 + ct) * 64 + lane];        // W1
      short8 b2 = *(const short8*)&bw[((ks + 4) * 8 + ct) * 64 + lane];  // W2
      acc[0][ct] = __builtin_amdgcn_mfma_f32_16x16x32_bf16(rf0, b1, acc[0][ct], 0, 0, 0);
      acc[0][ct] = __builtin_amdgcn_mfma_f32_16x16x32_bf16(m0, b2, acc[0][ct], 0, 0, 0);
      acc[1][ct] = __builtin_amdgcn_mfma_f32_16x16x32_bf16(rf1, b1, acc[1][ct], 0, 0, 0);
      acc[1][ct] = __builtin_amdgcn_mfma_f32_16x16x32_bf16(m1, b2, acc[1][ct], 0, 0, 0);
    }
  }

  // C/D layout: col = lane&15, row = (lane>>4)*4 + reg
  const int orow = (lane >> 4) * 4;
  const int ocol = lane & 15;
#pragma unroll
  for (int rt = 0; rt < 2; ++rt) {
    long rbase = Rw + rt * 16 + orow;
#pragma unroll
    for (int ct = 0; ct < 8; ++ct) {
#pragma unroll
      for (int q = 0; q < 4; ++q) {
        long rr = rbase + q;
        if (rr < NN) out[rr * DD + ct * 16 + ocol] = acc[rt][ct][q];
      }
    }
  }
}

extern "C" void kernel_launch(void* const* d_in, const int* in_sizes, int n_in,
                              void* d_out, int out_size, void* d_ws, size_t ws_size,
                              hipStream_t stream) {
  const float* emb = (const float*)d_in[0];
  const int* erow = (const int*)d_in[1];
  const int* ecol = (const int*)d_in[2];
  const float* eva = (const float*)d_in[3];
  const float* W1 = (const float*)d_in[4];
  const float* W2 = (const float*)d_in[5];
  float* out = (float*)d_out;

  // workspace layout (bytes), total 58,466,688 (same as proven last round):
  //   tbl     @ 0          : 25,600,000  (bf16 emb)
  //   rel     @ 25,600,000 : 25,600,000  (bf16 rel)
  //   offsets @ 51,200,000 : 400,128
  //   counts  @ 51,600,128 : 400,000  (aliased as cursor after scan)
  //   cpack   @ 52,000,128 : 6,400,000
  //   bsum    @ 58,400,128 : 512
  //   bpre    @ 58,400,640 : 512
  //   wpack   @ 58,401,152 : 65,536
  char* ws = (char*)d_ws;
  unsigned short* tbl = (unsigned short*)(ws);
  unsigned short* rel = (unsigned short*)(ws + 25600000);
  int* offsets = (int*)(ws + 51200000);
  int* counts = (int*)(ws + 51600128);
  int* cursor = counts;
  unsigned* cpack = (unsigned*)(ws + 52000128);
  int* bsum = (int*)(ws + 58400128);
  int* bpre = (int*)(ws + 58400640);
  uint4* wpack = (uint4*)(ws + 58401152);

  hipMemsetAsync(counts, 0, NN * sizeof(int), stream);
  k_cvt<<<6250, 256, 0, stream>>>(emb, (uint4*)tbl);
  k_count<<<1024, 256, 0, stream>>>(erow, counts);
  k_scan1<<<NBLK, 1024, 0, stream>>>(counts, offsets, bsum);
  k_scan2<<<1, 64, 0, stream>>>(bsum, bpre);
  k_scan3<<<NBLK, 1024, 0, stream>>>(offsets, cursor, bpre);
  k_scatter<<<1024, 256, 0, stream>>>(erow, ecol, eva, cursor, cpack);
  k_packw<<<16, 256, 0, stream>>>(W1, W2, wpack);
  k_spmm<<<NN / 4, 256, 0, stream>>>(offsets, cpack, tbl, (unsigned*)rel);
  k_phase2<<<(NN + 127) / 128, 256, 0, stream>>>(rel, tbl, wpack, out);
}